// Round 5
// baseline (292.139 us; speedup 1.0000x reference)
//
#include <hip/hip_runtime.h>
#include <cstdint>

#define B_ 2
#define S_ 2048
#define D_ 1024
#define H_ 16

typedef __bf16 bf16x8 __attribute__((ext_vector_type(8)));
typedef __bf16 bf16x4 __attribute__((ext_vector_type(4)));
typedef float  f32x4  __attribute__((ext_vector_type(4)));

// async global->LDS, 16B per lane; LDS dest = wave-uniform base + lane*16 (HW)
__device__ __forceinline__ void g2l16(const void* g, void* l) {
  auto* gp = reinterpret_cast<const __attribute__((address_space(1))) uint32_t*>(
      reinterpret_cast<uintptr_t>(g));
  auto* lp = reinterpret_cast<__attribute__((address_space(3))) uint32_t*>(
      reinterpret_cast<uintptr_t>(l));
  __builtin_amdgcn_global_load_lds(gp, lp, 16, 0, 0);
}

__device__ __forceinline__ float exp2_hw(float x) {
#if __has_builtin(__builtin_amdgcn_exp2f)
  return __builtin_amdgcn_exp2f(x);
#else
  return __exp2f(x);
#endif
}

// ---------------- K0: fp32 -> bf16 conversion ----------------
struct CvtArgs {
  const float* s[7];
  __bf16* d[7];
  int n[7];
};

__global__ __launch_bounds__(256) void k_cvt(CvtArgs a) {
  int t = blockIdx.y;
  long i = (long)blockIdx.x * blockDim.x + threadIdx.x;
  long base = i * 8;
  if (base >= a.n[t]) return;
  const float4* sp = (const float4*)(a.s[t] + base);
  float4 x = sp[0], y = sp[1];
  bf16x8 o;
  o[0] = (__bf16)x.x; o[1] = (__bf16)x.y; o[2] = (__bf16)x.z; o[3] = (__bf16)x.w;
  o[4] = (__bf16)y.x; o[5] = (__bf16)y.y; o[6] = (__bf16)y.z; o[7] = (__bf16)y.w;
  *(bf16x8*)(a.d[t] + base) = o;
}

// ---------------- K1: QKV projection GEMM (3-deep ring pipeline) ------------
__global__ __launch_bounds__(256, 3) void k_proj(
    const __bf16* __restrict__ Xq, const __bf16* __restrict__ Xk, const __bf16* __restrict__ Xv,
    const __bf16* __restrict__ Wq, const __bf16* __restrict__ Wk, const __bf16* __restrict__ Wv,
    const float* __restrict__ bq, const float* __restrict__ bk, const float* __restrict__ bv,
    __bf16* __restrict__ Oq, __bf16* __restrict__ Ok, __bf16* __restrict__ Ov)
{
  int z = blockIdx.z;
  const __bf16* X = (z == 0) ? Xq : (z == 1) ? Xk : Xv;
  const __bf16* W = (z == 0) ? Wq : (z == 1) ? Wk : Wv;
  const float* bias = (z == 0) ? bq : (z == 1) ? bk : bv;
  __bf16* O = (z == 0) ? Oq : (z == 1) ? Ok : Ov;
  float scale = (z == 0) ? 0.180336880111183f : 1.0f;  // 0.125 * log2(e)

  __shared__ bf16x8 As[3][512];
  __shared__ bf16x8 Bs[3][512];

  int t = threadIdx.x, lane = t & 63, w = t >> 6;
  int l15 = lane & 15, l4 = lane >> 4;
  int wr = w >> 1, wc = w & 1;
  int m0 = blockIdx.y * 128, n0 = blockIdx.x * 128;

  int srow = t >> 2, sc = t & 3;
  int ldsoff = __builtin_amdgcn_readfirstlane(w * 1024);
  const __bf16* Xs = X + (size_t)(m0 + srow) * 1024 + sc * 8;
  const __bf16* Wsp = W + (size_t)(n0 + srow) * 1024 + sc * 8;

#define PSTAGE(buf, kt)                                                        \
  {                                                                            \
    _Pragma("unroll")                                                          \
    for (int i = 0; i < 2; ++i) {                                              \
      int lo = __builtin_amdgcn_readfirstlane(i * 4096 + ldsoff);              \
      g2l16(Xs + (size_t)i * 64 * 1024 + (kt) * 32, (char*)As[buf] + lo);      \
      g2l16(Wsp + (size_t)i * 64 * 1024 + (kt) * 32, (char*)Bs[buf] + lo);     \
    }                                                                          \
  }

  f32x4 acc[4][4] = {};

  PSTAGE(0, 0)
  PSTAGE(1, 1)
  asm volatile("s_waitcnt vmcnt(4)" ::: "memory");  // stage0 landed; stage1 in flight
  __builtin_amdgcn_s_barrier();
  __builtin_amdgcn_sched_barrier(0);

  int ring = 0;
  for (int kt = 0; kt < 32; ++kt) {
    int cur = ring;
    int rp2 = (ring == 0) ? 2 : ring - 1;  // (ring+2)%3
    if (kt + 2 < 32) PSTAGE(rp2, kt + 2)
    __builtin_amdgcn_sched_barrier(0);

    bf16x8 af[4], bfr[4];
#pragma unroll
    for (int i = 0; i < 4; ++i) af[i] = As[cur][(wr * 64 + i * 16 + l15) * 4 + l4];
#pragma unroll
    for (int j = 0; j < 4; ++j) bfr[j] = Bs[cur][(wc * 64 + j * 16 + l15) * 4 + l4];
#pragma unroll
    for (int i = 0; i < 4; ++i)
#pragma unroll
      for (int j = 0; j < 4; ++j)
        acc[i][j] = __builtin_amdgcn_mfma_f32_16x16x32_bf16(af[i], bfr[j], acc[i][j], 0, 0, 0);

    if (kt < 30) {
      asm volatile("s_waitcnt vmcnt(4)" ::: "memory");  // next stage landed
      __builtin_amdgcn_s_barrier();
      __builtin_amdgcn_sched_barrier(0);
    } else if (kt == 30) {
      asm volatile("s_waitcnt vmcnt(0)" ::: "memory");
      __builtin_amdgcn_s_barrier();
      __builtin_amdgcn_sched_barrier(0);
    }
    ring = (ring == 2) ? 0 : ring + 1;
  }
#undef PSTAGE

#pragma unroll
  for (int j = 0; j < 4; ++j) {
    int col = n0 + wc * 64 + j * 16 + l15;
    float bv_ = bias[col];
    int h = col >> 6, hd = col & 63;
#pragma unroll
    for (int i = 0; i < 4; ++i) {
#pragma unroll
      for (int r = 0; r < 4; ++r) {
        int row = m0 + wr * 64 + i * 16 + l4 * 4 + r;
        int b = row >> 11, ss = row & 2047;
        float val = (acc[i][j][r] + bv_) * scale;
        O[(((size_t)b * H_ + h) * S_ + ss) * 64 + hd] = (__bf16)val;
      }
    }
  }
}

// ---------------- K1b: Vh [B,H,S,64] -> VhT [B,H,64,S] ----------------
__global__ __launch_bounds__(256) void k_trans(const __bf16* __restrict__ Vh,
                                               __bf16* __restrict__ VhT)
{
  __shared__ __bf16 Tt[64][72];
  int bid = blockIdx.x;
  int bh = bid >> 5, st = bid & 31;
  int t = threadIdx.x;
  int sr = t >> 2, dc = (t & 3) * 16;
  const __bf16* src = Vh + (((size_t)bh * S_) + st * 64 + sr) * 64 + dc;
  *(bf16x8*)&Tt[sr][dc] = *(const bf16x8*)src;
  *(bf16x8*)&Tt[sr][dc + 8] = *(const bf16x8*)(src + 8);
  __syncthreads();
  int dr = t >> 2, s0 = (t & 3) * 16;
  bf16x8 o0, o1;
#pragma unroll
  for (int ii = 0; ii < 8; ++ii) { o0[ii] = Tt[s0 + ii][dr]; o1[ii] = Tt[s0 + 8 + ii][dr]; }
  __bf16* dst = VhT + ((size_t)bh * 64 + dr) * S_ + st * 64 + s0;
  *(bf16x8*)dst = o0;
  *(bf16x8*)(dst + 8) = o1;
}

// ---------------- K2: attention, two-sweep, no-max softmax ----------------
// SWAPPED QK layout: mfma(K,Q) -> lane holds p[q=l15][k=t8*16+l4*4+r]:
// 4 consecutive k per lane => dwordx4 atten stores, ds_write_b64 P staging,
// b128 P reads at the PV A-fragment layout, scalar inv_l per lane.
__global__ __launch_bounds__(512, 4) void k_attn(
    const __bf16* __restrict__ Qh, const __bf16* __restrict__ Kh,
    const __bf16* __restrict__ VhT, float* __restrict__ atten,
    __bf16* __restrict__ ctxb)
{
  __shared__ bf16x8 KVl[3][1024];  // 3 x 16KB stages (A: 128 keys; B: 64K + 64V)
  __shared__ bf16x8 Pl[8 * 176];   // per-wave p: [16 q rows][88 bf16 stride]

  int bid = blockIdx.x;
  int sb = (bid & 7) * 64 + (bid >> 3);  // XCD swizzle (512 = 8*64, bijective)
  int bh = sb >> 4, qt = sb & 15;
  int t = threadIdx.x, lane = t & 63, w = t >> 6;
  int l15 = lane & 15, l4 = lane >> 4;
  int q0 = qt * 128 + w * 16;

  const __bf16* Qp = Qh + ((size_t)bh * S_ + q0) * 64;
  bf16x8 qf0 = *(const bf16x8*)(Qp + (size_t)l15 * 64 + l4 * 8);
  bf16x8 qf1 = *(const bf16x8*)(Qp + (size_t)l15 * 64 + 32 + l4 * 8);

  int srow = t >> 3, sc8 = t & 7;
  int scs = sc8 ^ (srow & 7);  // pre-swizzled global source (LDS dest linear)
  int wbase = __builtin_amdgcn_readfirstlane(w * 1024);

  const __bf16* KpS = Kh + (size_t)bh * S_ * 64 + (size_t)srow * 64 + scs * 8;
  const __bf16* VpS = VhT + (size_t)bh * 64 * S_ + (size_t)srow * S_ + scs * 8;

  // ---- pass A: softmax denominator; 16 iters x 128 keys, 3-deep ring ----
  float l_part = 0.f;

#define ASTAGE(buf, kt)                                                        \
  {                                                                            \
    g2l16(KpS + (size_t)(kt) * 8192, (char*)KVl[buf] + wbase);                 \
    g2l16(KpS + (size_t)(kt) * 8192 + 4096, (char*)KVl[buf] + 8192 + wbase);   \
  }

  ASTAGE(0, 0)
  ASTAGE(1, 1)
  asm volatile("s_waitcnt vmcnt(2)" ::: "memory");
  __builtin_amdgcn_s_barrier();
  __builtin_amdgcn_sched_barrier(0);

  {
    int ring = 0;
    for (int kt = 0; kt < 16; ++kt) {
      int cur = ring;
      int rp2 = (ring == 0) ? 2 : ring - 1;
      if (kt + 2 < 16) ASTAGE(rp2, kt + 2)
      __builtin_amdgcn_sched_barrier(0);

#pragma unroll
      for (int t8 = 0; t8 < 8; ++t8) {
        int kr = t8 * 16 + l15;
        bf16x8 kf0 = KVl[cur][kr * 8 + ((l4) ^ (kr & 7))];
        bf16x8 kf1 = KVl[cur][kr * 8 + ((4 + l4) ^ (kr & 7))];
        f32x4 a_ = {0.f, 0.f, 0.f, 0.f};
        a_ = __builtin_amdgcn_mfma_f32_16x16x32_bf16(kf0, qf0, a_, 0, 0, 0);  // swapped
        a_ = __builtin_amdgcn_mfma_f32_16x16x32_bf16(kf1, qf1, a_, 0, 0, 0);
#pragma unroll
        for (int r = 0; r < 4; ++r) l_part += exp2_hw(a_[r]);
      }

      if (kt < 14) {
        asm volatile("s_waitcnt vmcnt(2)" ::: "memory");
        __builtin_amdgcn_s_barrier();
        __builtin_amdgcn_sched_barrier(0);
      } else if (kt == 14) {
        asm volatile("s_waitcnt vmcnt(0)" ::: "memory");
        __builtin_amdgcn_s_barrier();
        __builtin_amdgcn_sched_barrier(0);
      }
      ring = (ring == 2) ? 0 : ring + 1;
    }
  }
#undef ASTAGE

  // lanes sharing q=l15 are {l15, l15+16, l15+32, l15+48}
  float inv_l;
  {
    float l = l_part;
    l += __shfl_xor(l, 16);
    l += __shfl_xor(l, 32);
    inv_l = 1.0f / l;
  }

  // all waves done reading pass-A buffers before pass B overwrites them
  __builtin_amdgcn_s_barrier();
  __builtin_amdgcn_sched_barrier(0);

  // ---- pass B: write atten (dwordx4) + accumulate ctx; 32 iters, 3-deep ----
  f32x4 ctx[4] = {};
  float* aRowT = atten + ((size_t)bh * S_ + q0 + l15) * S_;  // per-lane q row
  __bf16* PlW = (__bf16*)(Pl + w * 176);

#define BSTAGE(buf, kt)                                                        \
  {                                                                            \
    g2l16(KpS + (size_t)(kt) * 4096, (char*)KVl[buf] + wbase);                 \
    g2l16(VpS + (size_t)(kt) * 64, (char*)KVl[buf] + 8192 + wbase);            \
  }

  BSTAGE(0, 0)
  BSTAGE(1, 1)
  asm volatile("s_waitcnt vmcnt(2)" ::: "memory");
  __builtin_amdgcn_s_barrier();
  __builtin_amdgcn_sched_barrier(0);

  {
    int ring = 0;
    for (int kt = 0; kt < 32; ++kt) {
      int cur = ring;
      int rp2 = (ring == 0) ? 2 : ring - 1;

      f32x4 sc[4];
#pragma unroll
      for (int t8 = 0; t8 < 4; ++t8) {
        int kr = t8 * 16 + l15;
        bf16x8 kf0 = KVl[cur][kr * 8 + ((l4) ^ (kr & 7))];
        bf16x8 kf1 = KVl[cur][kr * 8 + ((4 + l4) ^ (kr & 7))];
        f32x4 a_ = {0.f, 0.f, 0.f, 0.f};
        a_ = __builtin_amdgcn_mfma_f32_16x16x32_bf16(kf0, qf0, a_, 0, 0, 0);  // swapped
        a_ = __builtin_amdgcn_mfma_f32_16x16x32_bf16(kf1, qf1, a_, 0, 0, 0);
        sc[t8] = a_;
      }

      // p[q=l15][k = kt*64 + t8*16 + l4*4 + r] : vectorized along k
#pragma unroll
      for (int t8 = 0; t8 < 4; ++t8) {
        f32x4 pv;
        bf16x4 pb;
#pragma unroll
        for (int r = 0; r < 4; ++r) {
          float p = exp2_hw(sc[t8][r]) * inv_l;
          pv[r] = p;
          pb[r] = (__bf16)p;
        }
        *(f32x4*)(aRowT + kt * 64 + t8 * 16 + l4 * 4) = pv;
        *(bf16x4*)(PlW + l15 * 88 + t8 * 16 + l4 * 4) = pb;
      }

#pragma unroll
      for (int kc = 0; kc < 2; ++kc) {
        bf16x8 pa = *(const bf16x8*)(PlW + l15 * 88 + kc * 32 + l4 * 8);
#pragma unroll
        for (int dt = 0; dt < 4; ++dt) {
          int vr = dt * 16 + l15;
          bf16x8 vf = KVl[cur][512 + vr * 8 + ((kc * 4 + l4) ^ (vr & 7))];
          ctx[dt] = __builtin_amdgcn_mfma_f32_16x16x32_bf16(pa, vf, ctx[dt], 0, 0, 0);
        }
      }

      // stores issued BEFORE next-next loads => vmcnt(10) keeps
      // st(t-1)+st(t)+L(t+2) in flight (2 iters of store hiding), drains L(t+1)
      __builtin_amdgcn_sched_barrier(0);
      if (kt + 2 < 32) BSTAGE(rp2, kt + 2)
      __builtin_amdgcn_sched_barrier(0);

      if (kt < 30) {
        asm volatile("s_waitcnt vmcnt(10)" ::: "memory");
        __builtin_amdgcn_s_barrier();
        __builtin_amdgcn_sched_barrier(0);
      } else if (kt == 30) {
        asm volatile("s_waitcnt vmcnt(4)" ::: "memory");
        __builtin_amdgcn_s_barrier();
        __builtin_amdgcn_sched_barrier(0);
      }
      ring = (ring == 2) ? 0 : ring + 1;
    }
  }
#undef BSTAGE

  // epilogue: ctx -> ctxb [B,S,H*64] bf16 (ctx rows q=l4*4+r, cols d=dt*16+l15)
  int b = bh >> 4, h = bh & 15;
#pragma unroll
  for (int dt = 0; dt < 4; ++dt) {
#pragma unroll
    for (int r = 0; r < 4; ++r) {
      size_t row = (size_t)b * S_ + q0 + l4 * 4 + r;
      ctxb[row * D_ + h * 64 + dt * 16 + l15] = (__bf16)ctx[dt][r];
    }
  }
}

// ---------------- K3: output projection -> fp32 d_out (3-deep ring) --------
__global__ __launch_bounds__(256, 3) void k_out(
    const __bf16* __restrict__ X, const __bf16* __restrict__ W,
    const float* __restrict__ bias, float* __restrict__ O)
{
  __shared__ bf16x8 As[3][512];
  __shared__ bf16x8 Bs[3][512];

  int t = threadIdx.x, lane = t & 63, w = t >> 6;
  int l15 = lane & 15, l4 = lane >> 4;
  int wr = w >> 1, wc = w & 1;
  int m0 = blockIdx.y * 128, n0 = blockIdx.x * 128;

  int srow = t >> 2, sc = t & 3;
  int ldsoff = __builtin_amdgcn_readfirstlane(w * 1024);
  const __bf16* Xs = X + (size_t)(m0 + srow) * 1024 + sc * 8;
  const __bf16* Wsp = W + (size_t)(n0 + srow) * 1024 + sc * 8;

#define PSTAGE(buf, kt)                                                        \
  {                                                                            \
    _Pragma("unroll")                                                          \
    for (int i = 0; i < 2; ++i) {                                              \
      int lo = __builtin_amdgcn_readfirstlane(i * 4096 + ldsoff);              \
      g2l16(Xs + (size_t)i * 64 * 1024 + (kt) * 32, (char*)As[buf] + lo);      \
      g2l16(Wsp + (size_t)i * 64 * 1024 + (kt) * 32, (char*)Bs[buf] + lo);     \
    }                                                                          \
  }

  f32x4 acc[4][4] = {};

  PSTAGE(0, 0)
  PSTAGE(1, 1)
  asm volatile("s_waitcnt vmcnt(4)" ::: "memory");
  __builtin_amdgcn_s_barrier();
  __builtin_amdgcn_sched_barrier(0);

  int ring = 0;
  for (int kt = 0; kt < 32; ++kt) {
    int cur = ring;
    int rp2 = (ring == 0) ? 2 : ring - 1;
    if (kt + 2 < 32) PSTAGE(rp2, kt + 2)
    __builtin_amdgcn_sched_barrier(0);

    bf16x8 af[4], bfr[4];
#pragma unroll
    for (int i = 0; i < 4; ++i) af[i] = As[cur][(wr * 64 + i * 16 + l15) * 4 + l4];
#pragma unroll
    for (int j = 0; j < 4; ++j) bfr[j] = Bs[cur][(wc * 64 + j * 16 + l15) * 4 + l4];
#pragma unroll
    for (int i = 0; i < 4; ++i)
#pragma unroll
      for (int j = 0; j < 4; ++j)
        acc[i][j] = __builtin_amdgcn_mfma_f32_16x16x32_bf16(af[i], bfr[j], acc[i][j], 0, 0, 0);

    if (kt < 30) {
      asm volatile("s_waitcnt vmcnt(4)" ::: "memory");
      __builtin_amdgcn_s_barrier();
      __builtin_amdgcn_sched_barrier(0);
    } else if (kt == 30) {
      asm volatile("s_waitcnt vmcnt(0)" ::: "memory");
      __builtin_amdgcn_s_barrier();
      __builtin_amdgcn_sched_barrier(0);
    }
    ring = (ring == 2) ? 0 : ring + 1;
  }
#undef PSTAGE

#pragma unroll
  for (int j = 0; j < 4; ++j) {
    int col = n0 + wc * 64 + j * 16 + l15;
    float bv_ = bias[col];
#pragma unroll
    for (int i = 0; i < 4; ++i) {
#pragma unroll
      for (int r = 0; r < 4; ++r) {
        int row = m0 + wr * 64 + i * 16 + l4 * 4 + r;
        O[(size_t)row * 1024 + col] = acc[i][j][r] + bv_;
      }
    }
  }
}

// ---------------- launch ----------------
extern "C" void kernel_launch(void* const* d_in, const int* in_sizes, int n_in,
                              void* d_out, int out_size, void* d_ws, size_t ws_size,
                              hipStream_t stream)
{
  const float* q  = (const float*)d_in[0];
  const float* k  = (const float*)d_in[1];
  const float* v  = (const float*)d_in[2];
  const float* Wq = (const float*)d_in[3];
  const float* bq = (const float*)d_in[4];
  const float* Wk = (const float*)d_in[5];
  const float* bk = (const float*)d_in[6];
  const float* Wv = (const float*)d_in[7];
  const float* bv = (const float*)d_in[8];
  const float* Wo = (const float*)d_in[9];
  const float* bo = (const float*)d_in[10];

  const size_t NBSD = (size_t)B_ * S_ * D_;   // 4194304
  const size_t NDD  = (size_t)D_ * D_;        // 1048576

  float* out = (float*)d_out;
  float* atten = out + NBSD;

  if (ws_size < 2 * (NBSD * 4 + NDD * 4 + NBSD * 4)) return;  // 67.1 MB needed

  __bf16* ws = (__bf16*)d_ws;
  __bf16* qb  = ws;
  __bf16* kb  = ws + NBSD;
  __bf16* vb  = ws + 2 * NBSD;
  __bf16* Wqb = ws + 3 * NBSD;
  __bf16* Wkb = Wqb + NDD;
  __bf16* Wvb = Wkb + NDD;
  __bf16* Wob = Wvb + NDD;
  __bf16* Qh  = Wob + NDD;
  __bf16* Kh  = Qh + NBSD;
  __bf16* Vh  = Kh + NBSD;
  __bf16* VhT = Vh + NBSD;
  __bf16* ctxb = qb;  // alias: qb dead after k_proj

  CvtArgs ca;
  ca.s[0] = q;  ca.d[0] = qb;  ca.n[0] = (int)NBSD;
  ca.s[1] = k;  ca.d[1] = kb;  ca.n[1] = (int)NBSD;
  ca.s[2] = v;  ca.d[2] = vb;  ca.n[2] = (int)NBSD;
  ca.s[3] = Wq; ca.d[3] = Wqb; ca.n[3] = (int)NDD;
  ca.s[4] = Wk; ca.d[4] = Wkb; ca.n[4] = (int)NDD;
  ca.s[5] = Wv; ca.d[5] = Wvb; ca.n[5] = (int)NDD;
  ca.s[6] = Wo; ca.d[6] = Wob; ca.n[6] = (int)NDD;

  k_cvt<<<dim3(2048, 7), 256, 0, stream>>>(ca);
  k_proj<<<dim3(8, 32, 3), 256, 0, stream>>>(qb, kb, vb, Wqb, Wkb, Wvb,
                                             bq, bk, bv, Qh, Kh, Vh);
  k_trans<<<dim3(1024), 256, 0, stream>>>(Vh, VhT);
  k_attn<<<dim3(512), 512, 0, stream>>>(Qh, Kh, VhT, atten, ctxb);
  k_out<<<dim3(8, 32), 256, 0, stream>>>(ctxb, Wob, bo, out);
}

// Round 6
// 261.458 us; speedup vs baseline: 1.1173x; 1.1173x over previous
//
#include <hip/hip_runtime.h>
#include <cstdint>

#define B_ 2
#define S_ 2048
#define D_ 1024
#define H_ 16

typedef __bf16 bf16x8 __attribute__((ext_vector_type(8)));
typedef float  f32x4  __attribute__((ext_vector_type(4)));

// async global->LDS, 16B per lane; LDS dest = wave-uniform base + lane*16 (HW)
__device__ __forceinline__ void g2l16(const void* g, void* l) {
  auto* gp = reinterpret_cast<const __attribute__((address_space(1))) uint32_t*>(
      reinterpret_cast<uintptr_t>(g));
  auto* lp = reinterpret_cast<__attribute__((address_space(3))) uint32_t*>(
      reinterpret_cast<uintptr_t>(l));
  __builtin_amdgcn_global_load_lds(gp, lp, 16, 0, 0);
}

__device__ __forceinline__ float exp2_hw(float x) {
#if __has_builtin(__builtin_amdgcn_exp2f)
  return __builtin_amdgcn_exp2f(x);
#else
  return __exp2f(x);
#endif
}

// ---------------- K0: fp32 -> bf16 conversion ----------------
struct CvtArgs {
  const float* s[7];
  __bf16* d[7];
  int n[7];
};

__global__ __launch_bounds__(256) void k_cvt(CvtArgs a) {
  int t = blockIdx.y;
  long i = (long)blockIdx.x * blockDim.x + threadIdx.x;
  long base = i * 8;
  if (base >= a.n[t]) return;
  const float4* sp = (const float4*)(a.s[t] + base);
  float4 x = sp[0], y = sp[1];
  bf16x8 o;
  o[0] = (__bf16)x.x; o[1] = (__bf16)x.y; o[2] = (__bf16)x.z; o[3] = (__bf16)x.w;
  o[4] = (__bf16)y.x; o[5] = (__bf16)y.y; o[6] = (__bf16)y.z; o[7] = (__bf16)y.w;
  *(bf16x8*)(a.d[t] + base) = o;
}

// ---------------- K1: QKV projection GEMM (3-deep ring pipeline) ------------
__global__ __launch_bounds__(256, 3) void k_proj(
    const __bf16* __restrict__ Xq, const __bf16* __restrict__ Xk, const __bf16* __restrict__ Xv,
    const __bf16* __restrict__ Wq, const __bf16* __restrict__ Wk, const __bf16* __restrict__ Wv,
    const float* __restrict__ bq, const float* __restrict__ bk, const float* __restrict__ bv,
    __bf16* __restrict__ Oq, __bf16* __restrict__ Ok, __bf16* __restrict__ Ov)
{
  int z = blockIdx.z;
  const __bf16* X = (z == 0) ? Xq : (z == 1) ? Xk : Xv;
  const __bf16* W = (z == 0) ? Wq : (z == 1) ? Wk : Wv;
  const float* bias = (z == 0) ? bq : (z == 1) ? bk : bv;
  __bf16* O = (z == 0) ? Oq : (z == 1) ? Ok : Ov;
  float scale = (z == 0) ? 0.180336880111183f : 1.0f;  // 0.125 * log2(e)

  __shared__ bf16x8 As[3][512];
  __shared__ bf16x8 Bs[3][512];

  int t = threadIdx.x, lane = t & 63, w = t >> 6;
  int l15 = lane & 15, l4 = lane >> 4;
  int wr = w >> 1, wc = w & 1;
  int m0 = blockIdx.y * 128, n0 = blockIdx.x * 128;

  int srow = t >> 2, sc = t & 3;
  int ldsoff = __builtin_amdgcn_readfirstlane(w * 1024);
  const __bf16* Xs = X + (size_t)(m0 + srow) * 1024 + sc * 8;
  const __bf16* Wsp = W + (size_t)(n0 + srow) * 1024 + sc * 8;

#define PSTAGE(buf, kt)                                                        \
  {                                                                            \
    _Pragma("unroll")                                                          \
    for (int i = 0; i < 2; ++i) {                                              \
      int lo = __builtin_amdgcn_readfirstlane(i * 4096 + ldsoff);              \
      g2l16(Xs + (size_t)i * 64 * 1024 + (kt) * 32, (char*)As[buf] + lo);      \
      g2l16(Wsp + (size_t)i * 64 * 1024 + (kt) * 32, (char*)Bs[buf] + lo);     \
    }                                                                          \
  }

  f32x4 acc[4][4] = {};

  PSTAGE(0, 0)
  PSTAGE(1, 1)
  asm volatile("s_waitcnt vmcnt(4)" ::: "memory");  // stage0 landed; stage1 in flight
  __builtin_amdgcn_s_barrier();
  __builtin_amdgcn_sched_barrier(0);

  int ring = 0;
  for (int kt = 0; kt < 32; ++kt) {
    int cur = ring;
    int rp2 = (ring == 0) ? 2 : ring - 1;  // (ring+2)%3
    if (kt + 2 < 32) PSTAGE(rp2, kt + 2)
    __builtin_amdgcn_sched_barrier(0);

    bf16x8 af[4], bfr[4];
#pragma unroll
    for (int i = 0; i < 4; ++i) af[i] = As[cur][(wr * 64 + i * 16 + l15) * 4 + l4];
#pragma unroll
    for (int j = 0; j < 4; ++j) bfr[j] = Bs[cur][(wc * 64 + j * 16 + l15) * 4 + l4];
#pragma unroll
    for (int i = 0; i < 4; ++i)
#pragma unroll
      for (int j = 0; j < 4; ++j)
        acc[i][j] = __builtin_amdgcn_mfma_f32_16x16x32_bf16(af[i], bfr[j], acc[i][j], 0, 0, 0);

    if (kt < 30) {
      asm volatile("s_waitcnt vmcnt(4)" ::: "memory");  // next stage landed
      __builtin_amdgcn_s_barrier();
      __builtin_amdgcn_sched_barrier(0);
    } else if (kt == 30) {
      asm volatile("s_waitcnt vmcnt(0)" ::: "memory");
      __builtin_amdgcn_s_barrier();
      __builtin_amdgcn_sched_barrier(0);
    }
    ring = (ring == 2) ? 0 : ring + 1;
  }
#undef PSTAGE

#pragma unroll
  for (int j = 0; j < 4; ++j) {
    int col = n0 + wc * 64 + j * 16 + l15;
    float bv_ = bias[col];
    int h = col >> 6, hd = col & 63;
#pragma unroll
    for (int i = 0; i < 4; ++i) {
#pragma unroll
      for (int r = 0; r < 4; ++r) {
        int row = m0 + wr * 64 + i * 16 + l4 * 4 + r;
        int b = row >> 11, ss = row & 2047;
        float val = (acc[i][j][r] + bv_) * scale;
        O[(((size_t)b * H_ + h) * S_ + ss) * 64 + hd] = (__bf16)val;
      }
    }
  }
}

// ---------------- K1b: Vh [B,H,S,64] -> VhT [B,H,64,S] ----------------
__global__ __launch_bounds__(256) void k_trans(const __bf16* __restrict__ Vh,
                                               __bf16* __restrict__ VhT)
{
  __shared__ __bf16 Tt[64][72];
  int bid = blockIdx.x;
  int bh = bid >> 5, st = bid & 31;
  int t = threadIdx.x;
  int sr = t >> 2, dc = (t & 3) * 16;
  const __bf16* src = Vh + (((size_t)bh * S_) + st * 64 + sr) * 64 + dc;
  *(bf16x8*)&Tt[sr][dc] = *(const bf16x8*)src;
  *(bf16x8*)&Tt[sr][dc + 8] = *(const bf16x8*)(src + 8);
  __syncthreads();
  int dr = t >> 2, s0 = (t & 3) * 16;
  bf16x8 o0, o1;
#pragma unroll
  for (int ii = 0; ii < 8; ++ii) { o0[ii] = Tt[s0 + ii][dr]; o1[ii] = Tt[s0 + 8 + ii][dr]; }
  __bf16* dst = VhT + ((size_t)bh * 64 + dr) * S_ + st * 64 + s0;
  *(bf16x8*)dst = o0;
  *(bf16x8*)(dst + 8) = o1;
}

// ---------------- K2: attention, two-sweep, no-max softmax ----------------
// Pass A: 128-key chunks, 3-deep ring, counted vmcnt(2).
// Pass B: 64-key chunks, 3-deep K/V ring, constant vmcnt(18), PLAIN stores.
__global__ __launch_bounds__(512, 4) void k_attn(
    const __bf16* __restrict__ Qh, const __bf16* __restrict__ Kh,
    const __bf16* __restrict__ VhT, float* __restrict__ atten,
    __bf16* __restrict__ ctxb)
{
  __shared__ bf16x8 KVl[3][1024];  // 3 x 16KB stages (A: 128 keys; B: 64K + 64V)
  __shared__ bf16x8 Pl[8 * 176];   // per-wave p: [16 rows][11 chunks]

  int bid = blockIdx.x;
  int sb = (bid & 7) * 64 + (bid >> 3);  // XCD swizzle (512 = 8*64, bijective)
  int bh = sb >> 4, qt = sb & 15;
  int t = threadIdx.x, lane = t & 63, w = t >> 6;
  int l15 = lane & 15, l4 = lane >> 4;
  int q0 = qt * 128 + w * 16;

  const __bf16* Qp = Qh + ((size_t)bh * S_ + q0) * 64;
  bf16x8 qf0 = *(const bf16x8*)(Qp + (size_t)l15 * 64 + l4 * 8);
  bf16x8 qf1 = *(const bf16x8*)(Qp + (size_t)l15 * 64 + 32 + l4 * 8);

  int srow = t >> 3, sc8 = t & 7;
  int scs = sc8 ^ (srow & 7);  // pre-swizzled global source (LDS dest linear)
  int wbase = __builtin_amdgcn_readfirstlane(w * 1024);

  const __bf16* KpS = Kh + (size_t)bh * S_ * 64 + (size_t)srow * 64 + scs * 8;
  const __bf16* VpS = VhT + (size_t)bh * 64 * S_ + (size_t)srow * S_ + scs * 8;

  // ---- pass A: softmax denominator; 16 iters x 128 keys, 3-deep ----
  float l_part[4] = {0.f, 0.f, 0.f, 0.f};

#define ASTAGE(buf, kt)                                                        \
  {                                                                            \
    g2l16(KpS + (size_t)(kt) * 8192, (char*)KVl[buf] + wbase);                 \
    g2l16(KpS + (size_t)(kt) * 8192 + 4096, (char*)KVl[buf] + 8192 + wbase);   \
  }

  ASTAGE(0, 0)
  ASTAGE(1, 1)
  asm volatile("s_waitcnt vmcnt(2)" ::: "memory");
  __builtin_amdgcn_s_barrier();
  __builtin_amdgcn_sched_barrier(0);

  {
    int ring = 0;
    for (int kt = 0; kt < 16; ++kt) {
      int cur = ring;
      int rp2 = (ring == 0) ? 2 : ring - 1;
      if (kt + 2 < 16) ASTAGE(rp2, kt + 2)
      __builtin_amdgcn_sched_barrier(0);

#pragma unroll
      for (int t8 = 0; t8 < 8; ++t8) {
        int kr = t8 * 16 + l15;
        bf16x8 kf0 = KVl[cur][kr * 8 + ((l4) ^ (kr & 7))];
        bf16x8 kf1 = KVl[cur][kr * 8 + ((4 + l4) ^ (kr & 7))];
        f32x4 a_ = {0.f, 0.f, 0.f, 0.f};
        a_ = __builtin_amdgcn_mfma_f32_16x16x32_bf16(qf0, kf0, a_, 0, 0, 0);
        a_ = __builtin_amdgcn_mfma_f32_16x16x32_bf16(qf1, kf1, a_, 0, 0, 0);
#pragma unroll
        for (int r = 0; r < 4; ++r) l_part[r] += exp2_hw(a_[r]);
      }

      if (kt < 14) {
        asm volatile("s_waitcnt vmcnt(2)" ::: "memory");
        __builtin_amdgcn_s_barrier();
        __builtin_amdgcn_sched_barrier(0);
      } else if (kt == 14) {
        asm volatile("s_waitcnt vmcnt(0)" ::: "memory");
        __builtin_amdgcn_s_barrier();
        __builtin_amdgcn_sched_barrier(0);
      }
      ring = (ring == 2) ? 0 : ring + 1;
    }
  }
#undef ASTAGE

  float inv_l[4];
#pragma unroll
  for (int r = 0; r < 4; ++r) {
    float l = l_part[r];
    l += __shfl_xor(l, 1);
    l += __shfl_xor(l, 2);
    l += __shfl_xor(l, 4);
    l += __shfl_xor(l, 8);
    inv_l[r] = 1.0f / l;
  }

  // all waves done reading pass-A buffers before pass B overwrites them
  __builtin_amdgcn_s_barrier();
  __builtin_amdgcn_sched_barrier(0);

  // ---- pass B: write atten + accumulate ctx; 32 iters x 64 keys ----
  f32x4 ctx[4] = {};
  float* aRow = atten + ((size_t)bh * S_ + q0) * S_;
  __bf16* PlW = (__bf16*)(Pl + w * 176);

#define BSTAGE(buf, kt)                                                        \
  {                                                                            \
    g2l16(KpS + (size_t)(kt) * 4096, (char*)KVl[buf] + wbase);                 \
    g2l16(VpS + (size_t)(kt) * 64, (char*)KVl[buf] + 8192 + wbase);            \
  }

  BSTAGE(0, 0)
  BSTAGE(1, 1)
  asm volatile("s_waitcnt vmcnt(2)" ::: "memory");
  __builtin_amdgcn_s_barrier();
  __builtin_amdgcn_sched_barrier(0);

  {
    int ring = 0;
    for (int kt = 0; kt < 32; ++kt) {
      int cur = ring;
      int rp2 = (ring == 0) ? 2 : ring - 1;
      if (kt + 2 < 32) BSTAGE(rp2, kt + 2)
      // pin: stage loads issue BEFORE the 16 atten stores, so vmcnt counting holds
      __builtin_amdgcn_sched_barrier(0);

      f32x4 sc[4];
#pragma unroll
      for (int t8 = 0; t8 < 4; ++t8) {
        int kr = t8 * 16 + l15;
        bf16x8 kf0 = KVl[cur][kr * 8 + ((l4) ^ (kr & 7))];
        bf16x8 kf1 = KVl[cur][kr * 8 + ((4 + l4) ^ (kr & 7))];
        f32x4 a_ = {0.f, 0.f, 0.f, 0.f};
        a_ = __builtin_amdgcn_mfma_f32_16x16x32_bf16(qf0, kf0, a_, 0, 0, 0);
        a_ = __builtin_amdgcn_mfma_f32_16x16x32_bf16(qf1, kf1, a_, 0, 0, 0);
        sc[t8] = a_;
      }

#pragma unroll
      for (int t8 = 0; t8 < 4; ++t8) {
#pragma unroll
        for (int r = 0; r < 4; ++r) {
          float p = exp2_hw(sc[t8][r]) * inv_l[r];
          aRow[(size_t)(l4 * 4 + r) * S_ + kt * 64 + t8 * 16 + l15] = p;
          PlW[(l4 * 4 + r) * 88 + t8 * 16 + l15] = (__bf16)p;
        }
      }

#pragma unroll
      for (int kc = 0; kc < 2; ++kc) {
        bf16x8 pa = Pl[w * 176 + l15 * 11 + kc * 4 + l4];
#pragma unroll
        for (int dt = 0; dt < 4; ++dt) {
          int vr = dt * 16 + l15;
          bf16x8 vf = KVl[cur][512 + vr * 8 + ((kc * 4 + l4) ^ (vr & 7))];
          ctx[dt] = __builtin_amdgcn_mfma_f32_16x16x32_bf16(pa, vf, ctx[dt], 0, 0, 0);
        }
      }

      if (kt < 31) {
        // steady state: newest-18 = L(t+2)2 + St(t)16 -> forces L(t+1) landed,
        // lets this iter's stores stream across the barrier
        asm volatile("s_waitcnt vmcnt(18)" ::: "memory");
        __builtin_amdgcn_s_barrier();
        __builtin_amdgcn_sched_barrier(0);
      }
      ring = (ring == 2) ? 0 : ring + 1;
    }
  }
#undef BSTAGE

  // epilogue: ctx -> ctxb [B,S,H*64] bf16
  int b = bh >> 4, h = bh & 15;
#pragma unroll
  for (int dt = 0; dt < 4; ++dt) {
#pragma unroll
    for (int r = 0; r < 4; ++r) {
      size_t row = (size_t)b * S_ + q0 + l4 * 4 + r;
      ctxb[row * D_ + h * 64 + dt * 16 + l15] = (__bf16)ctx[dt][r];
    }
  }
}

// ---------------- K3: output projection -> fp32 d_out (3-deep ring) --------
__global__ __launch_bounds__(256, 3) void k_out(
    const __bf16* __restrict__ X, const __bf16* __restrict__ W,
    const float* __restrict__ bias, float* __restrict__ O)
{
  __shared__ bf16x8 As[3][512];
  __shared__ bf16x8 Bs[3][512];

  int t = threadIdx.x, lane = t & 63, w = t >> 6;
  int l15 = lane & 15, l4 = lane >> 4;
  int wr = w >> 1, wc = w & 1;
  int m0 = blockIdx.y * 128, n0 = blockIdx.x * 128;

  int srow = t >> 2, sc = t & 3;
  int ldsoff = __builtin_amdgcn_readfirstlane(w * 1024);
  const __bf16* Xs = X + (size_t)(m0 + srow) * 1024 + sc * 8;
  const __bf16* Wsp = W + (size_t)(n0 + srow) * 1024 + sc * 8;

#define PSTAGE(buf, kt)                                                        \
  {                                                                            \
    _Pragma("unroll")                                                          \
    for (int i = 0; i < 2; ++i) {                                              \
      int lo = __builtin_amdgcn_readfirstlane(i * 4096 + ldsoff);              \
      g2l16(Xs + (size_t)i * 64 * 1024 + (kt) * 32, (char*)As[buf] + lo);      \
      g2l16(Wsp + (size_t)i * 64 * 1024 + (kt) * 32, (char*)Bs[buf] + lo);     \
    }                                                                          \
  }

  f32x4 acc[4][4] = {};

  PSTAGE(0, 0)
  PSTAGE(1, 1)
  asm volatile("s_waitcnt vmcnt(4)" ::: "memory");
  __builtin_amdgcn_s_barrier();
  __builtin_amdgcn_sched_barrier(0);

  int ring = 0;
  for (int kt = 0; kt < 32; ++kt) {
    int cur = ring;
    int rp2 = (ring == 0) ? 2 : ring - 1;
    if (kt + 2 < 32) PSTAGE(rp2, kt + 2)
    __builtin_amdgcn_sched_barrier(0);

    bf16x8 af[4], bfr[4];
#pragma unroll
    for (int i = 0; i < 4; ++i) af[i] = As[cur][(wr * 64 + i * 16 + l15) * 4 + l4];
#pragma unroll
    for (int j = 0; j < 4; ++j) bfr[j] = Bs[cur][(wc * 64 + j * 16 + l15) * 4 + l4];
#pragma unroll
    for (int i = 0; i < 4; ++i)
#pragma unroll
      for (int j = 0; j < 4; ++j)
        acc[i][j] = __builtin_amdgcn_mfma_f32_16x16x32_bf16(af[i], bfr[j], acc[i][j], 0, 0, 0);

    if (kt < 30) {
      asm volatile("s_waitcnt vmcnt(4)" ::: "memory");
      __builtin_amdgcn_s_barrier();
      __builtin_amdgcn_sched_barrier(0);
    } else if (kt == 30) {
      asm volatile("s_waitcnt vmcnt(0)" ::: "memory");
      __builtin_amdgcn_s_barrier();
      __builtin_amdgcn_sched_barrier(0);
    }
    ring = (ring == 2) ? 0 : ring + 1;
  }
#undef PSTAGE

#pragma unroll
  for (int j = 0; j < 4; ++j) {
    int col = n0 + wc * 64 + j * 16 + l15;
    float bv_ = bias[col];
#pragma unroll
    for (int i = 0; i < 4; ++i) {
#pragma unroll
      for (int r = 0; r < 4; ++r) {
        int row = m0 + wr * 64 + i * 16 + l4 * 4 + r;
        O[(size_t)row * 1024 + col] = acc[i][j][r] + bv_;
      }
    }
  }
}

// ---------------- launch ----------------
extern "C" void kernel_launch(void* const* d_in, const int* in_sizes, int n_in,
                              void* d_out, int out_size, void* d_ws, size_t ws_size,
                              hipStream_t stream)
{
  const float* q  = (const float*)d_in[0];
  const float* k  = (const float*)d_in[1];
  const float* v  = (const float*)d_in[2];
  const float* Wq = (const float*)d_in[3];
  const float* bq = (const float*)d_in[4];
  const float* Wk = (const float*)d_in[5];
  const float* bk = (const float*)d_in[6];
  const float* Wv = (const float*)d_in[7];
  const float* bv = (const float*)d_in[8];
  const float* Wo = (const float*)d_in[9];
  const float* bo = (const float*)d_in[10];

  const size_t NBSD = (size_t)B_ * S_ * D_;   // 4194304
  const size_t NDD  = (size_t)D_ * D_;        // 1048576

  float* out = (float*)d_out;
  float* atten = out + NBSD;

  if (ws_size < 2 * (NBSD * 4 + NDD * 4 + NBSD * 4)) return;  // 67.1 MB needed

  __bf16* ws = (__bf16*)d_ws;
  __bf16* qb  = ws;
  __bf16* kb  = ws + NBSD;
  __bf16* vb  = ws + 2 * NBSD;
  __bf16* Wqb = ws + 3 * NBSD;
  __bf16* Wkb = Wqb + NDD;
  __bf16* Wvb = Wkb + NDD;
  __bf16* Wob = Wvb + NDD;
  __bf16* Qh  = Wob + NDD;
  __bf16* Kh  = Qh + NBSD;
  __bf16* Vh  = Kh + NBSD;
  __bf16* VhT = Vh + NBSD;
  __bf16* ctxb = qb;  // alias: qb dead after k_proj

  CvtArgs ca;
  ca.s[0] = q;  ca.d[0] = qb;  ca.n[0] = (int)NBSD;
  ca.s[1] = k;  ca.d[1] = kb;  ca.n[1] = (int)NBSD;
  ca.s[2] = v;  ca.d[2] = vb;  ca.n[2] = (int)NBSD;
  ca.s[3] = Wq; ca.d[3] = Wqb; ca.n[3] = (int)NDD;
  ca.s[4] = Wk; ca.d[4] = Wkb; ca.n[4] = (int)NDD;
  ca.s[5] = Wv; ca.d[5] = Wvb; ca.n[5] = (int)NDD;
  ca.s[6] = Wo; ca.d[6] = Wob; ca.n[6] = (int)NDD;

  k_cvt<<<dim3(2048, 7), 256, 0, stream>>>(ca);
  k_proj<<<dim3(8, 32, 3), 256, 0, stream>>>(qb, kb, vb, Wqb, Wkb, Wvb,
                                             bq, bk, bv, Qh, Kh, Vh);
  k_trans<<<dim3(1024), 256, 0, stream>>>(Vh, VhT);
  k_attn<<<dim3(512), 512, 0, stream>>>(Qh, Kh, VhT, atten, ctxb);
  k_out<<<dim3(8, 32), 256, 0, stream>>>(ctxb, Wob, bo, out);
}

// Round 7
// 256.630 us; speedup vs baseline: 1.1384x; 1.0188x over previous
//
#include <hip/hip_runtime.h>
#include <cstdint>

#define B_ 2
#define S_ 2048
#define D_ 1024
#define H_ 16

typedef __bf16 bf16x8 __attribute__((ext_vector_type(8)));
typedef __bf16 bf16x4 __attribute__((ext_vector_type(4)));
typedef float  f32x4  __attribute__((ext_vector_type(4)));

// async global->LDS, 16B per lane; LDS dest = wave-uniform base + lane*16 (HW)
__device__ __forceinline__ void g2l16(const void* g, void* l) {
  auto* gp = reinterpret_cast<const __attribute__((address_space(1))) uint32_t*>(
      reinterpret_cast<uintptr_t>(g));
  auto* lp = reinterpret_cast<__attribute__((address_space(3))) uint32_t*>(
      reinterpret_cast<uintptr_t>(l));
  __builtin_amdgcn_global_load_lds(gp, lp, 16, 0, 0);
}

__device__ __forceinline__ float exp2_hw(float x) {
#if __has_builtin(__builtin_amdgcn_exp2f)
  return __builtin_amdgcn_exp2f(x);
#else
  return __exp2f(x);
#endif
}

// ---------------- K0: fp32 -> bf16 conversion (WEIGHTS ONLY now) ------------
struct CvtArgs {
  const float* s[4];
  __bf16* d[4];
};

__global__ __launch_bounds__(256) void k_cvt(CvtArgs a) {
  int t = blockIdx.y;
  long base = ((long)blockIdx.x * blockDim.x + threadIdx.x) * 8;
  const float4* sp = (const float4*)(a.s[t] + base);
  float4 x = sp[0], y = sp[1];
  bf16x8 o;
  o[0] = (__bf16)x.x; o[1] = (__bf16)x.y; o[2] = (__bf16)x.z; o[3] = (__bf16)x.w;
  o[4] = (__bf16)y.x; o[5] = (__bf16)y.y; o[6] = (__bf16)y.z; o[7] = (__bf16)y.w;
  *(bf16x8*)(a.d[t] + base) = o;
}

// ---------------- K1: QKV projection GEMM, fp32 X input ---------------------
// A (X) reg-staged fp32->bf16 (1-iter lookahead); B (W bf16) g2l16 3-ring
// (2-iter lookahead, vmcnt(2) steady). z==2 writes V^T via LDS transpose.
__global__ __launch_bounds__(256, 3) void k_proj(
    const float* __restrict__ Xq, const float* __restrict__ Xk, const float* __restrict__ Xv,
    const __bf16* __restrict__ Wq, const __bf16* __restrict__ Wk, const __bf16* __restrict__ Wv,
    const float* __restrict__ bq, const float* __restrict__ bk, const float* __restrict__ bv,
    __bf16* __restrict__ Oq, __bf16* __restrict__ Ok, __bf16* __restrict__ OvT)
{
  int z = blockIdx.z;
  const float* X = (z == 0) ? Xq : (z == 1) ? Xk : Xv;
  const __bf16* W = (z == 0) ? Wq : (z == 1) ? Wk : Wv;
  const float* bias = (z == 0) ? bq : (z == 1) ? bk : bv;
  float scale = (z == 0) ? 0.180336880111183f : 1.0f;  // 0.125 * log2(e)

  __shared__ __align__(16) char smem[40960];  // As[2] 16K + Bs[3] 24K; Tt reuses
  bf16x8 (*As)[512] = (bf16x8(*)[512])smem;
  bf16x8 (*Bs)[512] = (bf16x8(*)[512])(smem + 16384);

  int t = threadIdx.x, lane = t & 63, w = t >> 6;
  int l15 = lane & 15, l4 = lane >> 4;
  int wr = w >> 1, wc = w & 1;
  int m0 = blockIdx.y * 128, n0 = blockIdx.x * 128;

  // A staging: thread covers row=t>>1, 16 k at (t&1)*16
  int arow = t >> 1, ac2 = (t & 1) * 2;
  const float* Xs = X + (size_t)(m0 + arow) * 1024 + (t & 1) * 16;
  // B staging: g2l16, rows srow + i*64
  int srow = t >> 2, sc = t & 3;
  const __bf16* Wsp = W + (size_t)(n0 + srow) * 1024 + sc * 8;
  int ldsoff = __builtin_amdgcn_readfirstlane(w * 1024);

  float4 a0, a1, a2, a3;

#define ALOAD(kt)                                                              \
  {                                                                            \
    const float4* ap = (const float4*)(Xs + (size_t)(kt) * 32);                \
    a0 = ap[0]; a1 = ap[1]; a2 = ap[2]; a3 = ap[3];                            \
  }
#define AWRITE(buf)                                                            \
  {                                                                            \
    bf16x8 lo, hi;                                                             \
    lo[0] = (__bf16)a0.x; lo[1] = (__bf16)a0.y; lo[2] = (__bf16)a0.z;          \
    lo[3] = (__bf16)a0.w; lo[4] = (__bf16)a1.x; lo[5] = (__bf16)a1.y;          \
    lo[6] = (__bf16)a1.z; lo[7] = (__bf16)a1.w;                                \
    hi[0] = (__bf16)a2.x; hi[1] = (__bf16)a2.y; hi[2] = (__bf16)a2.z;          \
    hi[3] = (__bf16)a2.w; hi[4] = (__bf16)a3.x; hi[5] = (__bf16)a3.y;          \
    hi[6] = (__bf16)a3.z; hi[7] = (__bf16)a3.w;                                \
    As[buf][arow * 4 + ac2] = lo;                                              \
    As[buf][arow * 4 + ac2 + 1] = hi;                                          \
  }
#define BSTG(buf, kt)                                                          \
  {                                                                            \
    _Pragma("unroll")                                                          \
    for (int i = 0; i < 2; ++i) {                                              \
      int lo_ = __builtin_amdgcn_readfirstlane(i * 4096 + ldsoff);             \
      g2l16(Wsp + (size_t)i * 64 * 1024 + (kt) * 32, (char*)Bs[buf] + lo_);    \
    }                                                                          \
  }

  f32x4 acc[4][4] = {};

  // prologue: B0(2), A0(4), B1(2) -> vmcnt(2) forces B0+A0
  BSTG(0, 0)
  ALOAD(0)
  BSTG(1, 1)
  asm volatile("s_waitcnt vmcnt(2)" ::: "memory");
  AWRITE(0)
  ALOAD(1)
  asm volatile("s_waitcnt lgkmcnt(0)" ::: "memory");
  __builtin_amdgcn_s_barrier();
  __builtin_amdgcn_sched_barrier(0);

  int bring = 0;  // Bs index holding B(kt)
  for (int kt = 0; kt < 32; ++kt) {
    int bcur = bring;
    int bp2 = (bring >= 1) ? bring - 1 : 2;  // (bring+2)%3
    int acur = kt & 1, anxt = acur ^ 1;
    if (kt + 2 < 32) BSTG(bp2, kt + 2)
    __builtin_amdgcn_sched_barrier(0);

    bf16x8 af[4], bfr[4];
#pragma unroll
    for (int i = 0; i < 4; ++i) af[i] = As[acur][(wr * 64 + i * 16 + l15) * 4 + l4];
#pragma unroll
    for (int j = 0; j < 4; ++j) bfr[j] = Bs[bcur][(wc * 64 + j * 16 + l15) * 4 + l4];
#pragma unroll
    for (int i = 0; i < 4; ++i)
#pragma unroll
      for (int j = 0; j < 4; ++j)
        acc[i][j] = __builtin_amdgcn_mfma_f32_16x16x32_bf16(af[i], bfr[j], acc[i][j], 0, 0, 0);
    __builtin_amdgcn_sched_barrier(0);

    if (kt + 1 < 32) {
      // in-flight oldest->newest: B(kt+1)2, A(kt+1)4, B(kt+2)2
      if (kt + 2 < 32) {
        asm volatile("s_waitcnt vmcnt(2)" ::: "memory");  // forces B(t+1)+A(t+1)
      } else {
        asm volatile("s_waitcnt vmcnt(0)" ::: "memory");
      }
      AWRITE(anxt)
      if (kt + 2 < 32) ALOAD(kt + 2)
      asm volatile("s_waitcnt lgkmcnt(0)" ::: "memory");
      __builtin_amdgcn_s_barrier();
      __builtin_amdgcn_sched_barrier(0);
    }
    bring = (bring == 2) ? 0 : bring + 1;
  }
#undef ALOAD
#undef AWRITE
#undef BSTG

  if (z == 2) {
    // V^T epilogue: acc -> LDS transpose tile -> coalesced VhT stores
    __syncthreads();  // staging LDS dead, safe to reuse
    __bf16* Tt = (__bf16*)smem;
    const int LDT = 136;  // 272 B rows: 16B-aligned, bank-shift 4
    int b = m0 >> 11, ss0 = m0 & 2047;
#pragma unroll
    for (int p = 0; p < 2; ++p) {
      if (wc == p) {
#pragma unroll
        for (int j = 0; j < 4; ++j) {
          float bv_ = bias[n0 + p * 64 + j * 16 + l15];
#pragma unroll
          for (int i = 0; i < 4; ++i) {
            bf16x4 pv;
#pragma unroll
            for (int r = 0; r < 4; ++r) pv[r] = (__bf16)(acc[i][j][r] + bv_);
            *(bf16x4*)&Tt[(j * 16 + l15) * LDT + wr * 64 + i * 16 + l4 * 4] = pv;
          }
        }
      }
      __syncthreads();
      int h = (n0 >> 6) + p;
      __bf16* dst = OvT + ((size_t)(b * H_ + h) * 64) * S_ + ss0;
#pragma unroll
      for (int it = 0; it < 4; ++it) {
        int nl = it * 16 + (t >> 4);
        int mc = (t & 15) * 8;
        bf16x8 vv = *(bf16x8*)&Tt[nl * LDT + mc];
        *(bf16x8*)(dst + (size_t)nl * S_ + mc) = vv;
      }
      __syncthreads();
    }
  } else {
    __bf16* O = (z == 0) ? Oq : Ok;
#pragma unroll
    for (int j = 0; j < 4; ++j) {
      int col = n0 + wc * 64 + j * 16 + l15;
      float bv_ = bias[col];
      int h = col >> 6, hd = col & 63;
#pragma unroll
      for (int i = 0; i < 4; ++i) {
#pragma unroll
        for (int r = 0; r < 4; ++r) {
          int row = m0 + wr * 64 + i * 16 + l4 * 4 + r;
          int b = row >> 11, ss = row & 2047;
          float val = (acc[i][j][r] + bv_) * scale;
          O[(((size_t)b * H_ + h) * S_ + ss) * 64 + hd] = (__bf16)val;
        }
      }
    }
  }
}

// ---------------- K2: attention, two-sweep, no-max softmax (R6 verbatim) ----
__global__ __launch_bounds__(512, 4) void k_attn(
    const __bf16* __restrict__ Qh, const __bf16* __restrict__ Kh,
    const __bf16* __restrict__ VhT, float* __restrict__ atten,
    __bf16* __restrict__ ctxb)
{
  __shared__ bf16x8 KVl[3][1024];  // 3 x 16KB stages (A: 128 keys; B: 64K + 64V)
  __shared__ bf16x8 Pl[8 * 176];   // per-wave p: [16 rows][11 chunks]

  int bid = blockIdx.x;
  int sb = (bid & 7) * 64 + (bid >> 3);  // XCD swizzle (512 = 8*64, bijective)
  int bh = sb >> 4, qt = sb & 15;
  int t = threadIdx.x, lane = t & 63, w = t >> 6;
  int l15 = lane & 15, l4 = lane >> 4;
  int q0 = qt * 128 + w * 16;

  const __bf16* Qp = Qh + ((size_t)bh * S_ + q0) * 64;
  bf16x8 qf0 = *(const bf16x8*)(Qp + (size_t)l15 * 64 + l4 * 8);
  bf16x8 qf1 = *(const bf16x8*)(Qp + (size_t)l15 * 64 + 32 + l4 * 8);

  int srow = t >> 3, sc8 = t & 7;
  int scs = sc8 ^ (srow & 7);  // pre-swizzled global source (LDS dest linear)
  int wbase = __builtin_amdgcn_readfirstlane(w * 1024);

  const __bf16* KpS = Kh + (size_t)bh * S_ * 64 + (size_t)srow * 64 + scs * 8;
  const __bf16* VpS = VhT + (size_t)bh * 64 * S_ + (size_t)srow * S_ + scs * 8;

  // ---- pass A: softmax denominator; 16 iters x 128 keys, 3-deep ----
  float l_part[4] = {0.f, 0.f, 0.f, 0.f};

#define ASTAGE(buf, kt)                                                        \
  {                                                                            \
    g2l16(KpS + (size_t)(kt) * 8192, (char*)KVl[buf] + wbase);                 \
    g2l16(KpS + (size_t)(kt) * 8192 + 4096, (char*)KVl[buf] + 8192 + wbase);   \
  }

  ASTAGE(0, 0)
  ASTAGE(1, 1)
  asm volatile("s_waitcnt vmcnt(2)" ::: "memory");
  __builtin_amdgcn_s_barrier();
  __builtin_amdgcn_sched_barrier(0);

  {
    int ring = 0;
    for (int kt = 0; kt < 16; ++kt) {
      int cur = ring;
      int rp2 = (ring == 0) ? 2 : ring - 1;
      if (kt + 2 < 16) ASTAGE(rp2, kt + 2)
      __builtin_amdgcn_sched_barrier(0);

#pragma unroll
      for (int t8 = 0; t8 < 8; ++t8) {
        int kr = t8 * 16 + l15;
        bf16x8 kf0 = KVl[cur][kr * 8 + ((l4) ^ (kr & 7))];
        bf16x8 kf1 = KVl[cur][kr * 8 + ((4 + l4) ^ (kr & 7))];
        f32x4 a_ = {0.f, 0.f, 0.f, 0.f};
        a_ = __builtin_amdgcn_mfma_f32_16x16x32_bf16(qf0, kf0, a_, 0, 0, 0);
        a_ = __builtin_amdgcn_mfma_f32_16x16x32_bf16(qf1, kf1, a_, 0, 0, 0);
#pragma unroll
        for (int r = 0; r < 4; ++r) l_part[r] += exp2_hw(a_[r]);
      }

      if (kt < 14) {
        asm volatile("s_waitcnt vmcnt(2)" ::: "memory");
        __builtin_amdgcn_s_barrier();
        __builtin_amdgcn_sched_barrier(0);
      } else if (kt == 14) {
        asm volatile("s_waitcnt vmcnt(0)" ::: "memory");
        __builtin_amdgcn_s_barrier();
        __builtin_amdgcn_sched_barrier(0);
      }
      ring = (ring == 2) ? 0 : ring + 1;
    }
  }
#undef ASTAGE

  float inv_l[4];
#pragma unroll
  for (int r = 0; r < 4; ++r) {
    float l = l_part[r];
    l += __shfl_xor(l, 1);
    l += __shfl_xor(l, 2);
    l += __shfl_xor(l, 4);
    l += __shfl_xor(l, 8);
    inv_l[r] = 1.0f / l;
  }

  // all waves done reading pass-A buffers before pass B overwrites them
  __builtin_amdgcn_s_barrier();
  __builtin_amdgcn_sched_barrier(0);

  // ---- pass B: write atten + accumulate ctx; 32 iters x 64 keys ----
  f32x4 ctx[4] = {};
  float* aRow = atten + ((size_t)bh * S_ + q0) * S_;
  __bf16* PlW = (__bf16*)(Pl + w * 176);

#define BSTAGE(buf, kt)                                                        \
  {                                                                            \
    g2l16(KpS + (size_t)(kt) * 4096, (char*)KVl[buf] + wbase);                 \
    g2l16(VpS + (size_t)(kt) * 64, (char*)KVl[buf] + 8192 + wbase);            \
  }

  BSTAGE(0, 0)
  BSTAGE(1, 1)
  asm volatile("s_waitcnt vmcnt(2)" ::: "memory");
  __builtin_amdgcn_s_barrier();
  __builtin_amdgcn_sched_barrier(0);

  {
    int ring = 0;
    for (int kt = 0; kt < 32; ++kt) {
      int cur = ring;
      int rp2 = (ring == 0) ? 2 : ring - 1;
      if (kt + 2 < 32) BSTAGE(rp2, kt + 2)
      // pin: stage loads issue BEFORE the 16 atten stores, so vmcnt counting holds
      __builtin_amdgcn_sched_barrier(0);

      f32x4 sc[4];
#pragma unroll
      for (int t8 = 0; t8 < 4; ++t8) {
        int kr = t8 * 16 + l15;
        bf16x8 kf0 = KVl[cur][kr * 8 + ((l4) ^ (kr & 7))];
        bf16x8 kf1 = KVl[cur][kr * 8 + ((4 + l4) ^ (kr & 7))];
        f32x4 a_ = {0.f, 0.f, 0.f, 0.f};
        a_ = __builtin_amdgcn_mfma_f32_16x16x32_bf16(qf0, kf0, a_, 0, 0, 0);
        a_ = __builtin_amdgcn_mfma_f32_16x16x32_bf16(qf1, kf1, a_, 0, 0, 0);
        sc[t8] = a_;
      }

#pragma unroll
      for (int t8 = 0; t8 < 4; ++t8) {
#pragma unroll
        for (int r = 0; r < 4; ++r) {
          float p = exp2_hw(sc[t8][r]) * inv_l[r];
          aRow[(size_t)(l4 * 4 + r) * S_ + kt * 64 + t8 * 16 + l15] = p;
          PlW[(l4 * 4 + r) * 88 + t8 * 16 + l15] = (__bf16)p;
        }
      }

#pragma unroll
      for (int kc = 0; kc < 2; ++kc) {
        bf16x8 pa = Pl[w * 176 + l15 * 11 + kc * 4 + l4];
#pragma unroll
        for (int dt = 0; dt < 4; ++dt) {
          int vr = dt * 16 + l15;
          bf16x8 vf = KVl[cur][512 + vr * 8 + ((kc * 4 + l4) ^ (vr & 7))];
          ctx[dt] = __builtin_amdgcn_mfma_f32_16x16x32_bf16(pa, vf, ctx[dt], 0, 0, 0);
        }
      }

      if (kt < 31) {
        // steady state: newest-18 = L(t+2)2 + St(t)16 -> forces L(t+1) landed
        asm volatile("s_waitcnt vmcnt(18)" ::: "memory");
        __builtin_amdgcn_s_barrier();
        __builtin_amdgcn_sched_barrier(0);
      }
      ring = (ring == 2) ? 0 : ring + 1;
    }
  }
#undef BSTAGE

  // epilogue: ctx -> ctxb [B,S,H*64] bf16
  int b = bh >> 4, h = bh & 15;
#pragma unroll
  for (int dt = 0; dt < 4; ++dt) {
#pragma unroll
    for (int r = 0; r < 4; ++r) {
      size_t row = (size_t)b * S_ + q0 + l4 * 4 + r;
      ctxb[row * D_ + h * 64 + dt * 16 + l15] = (__bf16)ctx[dt][r];
    }
  }
}

// ---------------- K3: output projection -> fp32 d_out (3-ring, R6 verbatim) -
__global__ __launch_bounds__(256, 3) void k_out(
    const __bf16* __restrict__ X, const __bf16* __restrict__ W,
    const float* __restrict__ bias, float* __restrict__ O)
{
  __shared__ bf16x8 As[3][512];
  __shared__ bf16x8 Bs[3][512];

  int t = threadIdx.x, lane = t & 63, w = t >> 6;
  int l15 = lane & 15, l4 = lane >> 4;
  int wr = w >> 1, wc = w & 1;
  int m0 = blockIdx.y * 128, n0 = blockIdx.x * 128;

  int srow = t >> 2, sc = t & 3;
  int ldsoff = __builtin_amdgcn_readfirstlane(w * 1024);
  const __bf16* Xs = X + (size_t)(m0 + srow) * 1024 + sc * 8;
  const __bf16* Wsp = W + (size_t)(n0 + srow) * 1024 + sc * 8;

#define PSTAGE(buf, kt)                                                        \
  {                                                                            \
    _Pragma("unroll")                                                          \
    for (int i = 0; i < 2; ++i) {                                              \
      int lo = __builtin_amdgcn_readfirstlane(i * 4096 + ldsoff);              \
      g2l16(Xs + (size_t)i * 64 * 1024 + (kt) * 32, (char*)As[buf] + lo);      \
      g2l16(Wsp + (size_t)i * 64 * 1024 + (kt) * 32, (char*)Bs[buf] + lo);     \
    }                                                                          \
  }

  f32x4 acc[4][4] = {};

  PSTAGE(0, 0)
  PSTAGE(1, 1)
  asm volatile("s_waitcnt vmcnt(4)" ::: "memory");
  __builtin_amdgcn_s_barrier();
  __builtin_amdgcn_sched_barrier(0);

  int ring = 0;
  for (int kt = 0; kt < 32; ++kt) {
    int cur = ring;
    int rp2 = (ring == 0) ? 2 : ring - 1;
    if (kt + 2 < 32) PSTAGE(rp2, kt + 2)
    __builtin_amdgcn_sched_barrier(0);

    bf16x8 af[4], bfr[4];
#pragma unroll
    for (int i = 0; i < 4; ++i) af[i] = As[cur][(wr * 64 + i * 16 + l15) * 4 + l4];
#pragma unroll
    for (int j = 0; j < 4; ++j) bfr[j] = Bs[cur][(wc * 64 + j * 16 + l15) * 4 + l4];
#pragma unroll
    for (int i = 0; i < 4; ++i)
#pragma unroll
      for (int j = 0; j < 4; ++j)
        acc[i][j] = __builtin_amdgcn_mfma_f32_16x16x32_bf16(af[i], bfr[j], acc[i][j], 0, 0, 0);

    if (kt < 30) {
      asm volatile("s_waitcnt vmcnt(4)" ::: "memory");
      __builtin_amdgcn_s_barrier();
      __builtin_amdgcn_sched_barrier(0);
    } else if (kt == 30) {
      asm volatile("s_waitcnt vmcnt(0)" ::: "memory");
      __builtin_amdgcn_s_barrier();
      __builtin_amdgcn_sched_barrier(0);
    }
    ring = (ring == 2) ? 0 : ring + 1;
  }
#undef PSTAGE

#pragma unroll
  for (int j = 0; j < 4; ++j) {
    int col = n0 + wc * 64 + j * 16 + l15;
    float bv_ = bias[col];
#pragma unroll
    for (int i = 0; i < 4; ++i) {
#pragma unroll
      for (int r = 0; r < 4; ++r) {
        int row = m0 + wr * 64 + i * 16 + l4 * 4 + r;
        O[(size_t)row * 1024 + col] = acc[i][j][r] + bv_;
      }
    }
  }
}

// ---------------- launch ----------------
extern "C" void kernel_launch(void* const* d_in, const int* in_sizes, int n_in,
                              void* d_out, int out_size, void* d_ws, size_t ws_size,
                              hipStream_t stream)
{
  const float* q  = (const float*)d_in[0];
  const float* k  = (const float*)d_in[1];
  const float* v  = (const float*)d_in[2];
  const float* Wq = (const float*)d_in[3];
  const float* bq = (const float*)d_in[4];
  const float* Wk = (const float*)d_in[5];
  const float* bk = (const float*)d_in[6];
  const float* Wv = (const float*)d_in[7];
  const float* bv = (const float*)d_in[8];
  const float* Wo = (const float*)d_in[9];
  const float* bo = (const float*)d_in[10];

  const size_t NBSD = (size_t)B_ * S_ * D_;   // 4194304
  const size_t NDD  = (size_t)D_ * D_;        // 1048576

  float* out = (float*)d_out;
  float* atten = out + NBSD;

  if (ws_size < (4 * NDD + 4 * NBSD) * 2) return;  // ~41.9 MB needed

  __bf16* ws = (__bf16*)d_ws;
  __bf16* Wqb = ws;
  __bf16* Wkb = Wqb + NDD;
  __bf16* Wvb = Wkb + NDD;
  __bf16* Wob = Wvb + NDD;
  __bf16* Qh  = Wob + NDD;
  __bf16* Kh  = Qh + NBSD;
  __bf16* VhT = Kh + NBSD;
  __bf16* ctxb = VhT + NBSD;

  CvtArgs ca;
  ca.s[0] = Wq; ca.d[0] = Wqb;
  ca.s[1] = Wk; ca.d[1] = Wkb;
  ca.s[2] = Wv; ca.d[2] = Wvb;
  ca.s[3] = Wo; ca.d[3] = Wob;

  k_cvt<<<dim3(512, 4), 256, 0, stream>>>(ca);
  k_proj<<<dim3(8, 32, 3), 256, 0, stream>>>(q, k, v, Wqb, Wkb, Wvb,
                                             bq, bk, bv, Qh, Kh, VhT);
  k_attn<<<dim3(512), 512, 0, stream>>>(Qh, Kh, VhT, atten, ctxb);
  k_out<<<dim3(8, 32), 256, 0, stream>>>(ctxb, Wob, bo, out);
}

// Round 8
// 240.058 us; speedup vs baseline: 1.2170x; 1.0690x over previous
//
#include <hip/hip_runtime.h>
#include <cstdint>

#define B_ 2
#define S_ 2048
#define D_ 1024
#define H_ 16

typedef __bf16 bf16x8 __attribute__((ext_vector_type(8)));
typedef __bf16 bf16x4 __attribute__((ext_vector_type(4)));
typedef float  f32x4  __attribute__((ext_vector_type(4)));

// async global->LDS, 16B per lane; LDS dest = wave-uniform base + lane*16 (HW)
__device__ __forceinline__ void g2l16(const void* g, void* l) {
  auto* gp = reinterpret_cast<const __attribute__((address_space(1))) uint32_t*>(
      reinterpret_cast<uintptr_t>(g));
  auto* lp = reinterpret_cast<__attribute__((address_space(3))) uint32_t*>(
      reinterpret_cast<uintptr_t>(l));
  __builtin_amdgcn_global_load_lds(gp, lp, 16, 0, 0);
}

__device__ __forceinline__ float exp2_hw(float x) {
#if __has_builtin(__builtin_amdgcn_exp2f)
  return __builtin_amdgcn_exp2f(x);
#else
  return __exp2f(x);
#endif
}

// ---------------- K0: fp32 -> bf16 conversion (WEIGHTS ONLY) ----------------
struct CvtArgs {
  const float* s[4];
  __bf16* d[4];
};

__global__ __launch_bounds__(256) void k_cvt(CvtArgs a) {
  int t = blockIdx.y;
  long base = ((long)blockIdx.x * blockDim.x + threadIdx.x) * 8;
  const float4* sp = (const float4*)(a.s[t] + base);
  float4 x = sp[0], y = sp[1];
  bf16x8 o;
  o[0] = (__bf16)x.x; o[1] = (__bf16)x.y; o[2] = (__bf16)x.z; o[3] = (__bf16)x.w;
  o[4] = (__bf16)y.x; o[5] = (__bf16)y.y; o[6] = (__bf16)y.z; o[7] = (__bf16)y.w;
  *(bf16x8*)(a.d[t] + base) = o;
}

// ---------------- K1: QKV projection GEMM, fp32 X input ---------------------
// 1-D grid 768, XCD-clustered remap: the 8 n-blocks sharing an X panel land on
// the SAME XCD (bid%8 == group%8), co-resident -> X panel fetched once per L2.
__global__ __launch_bounds__(256, 3) void k_proj(
    const float* __restrict__ Xq, const float* __restrict__ Xk, const float* __restrict__ Xv,
    const __bf16* __restrict__ Wq, const __bf16* __restrict__ Wk, const __bf16* __restrict__ Wv,
    const float* __restrict__ bq, const float* __restrict__ bk, const float* __restrict__ bv,
    __bf16* __restrict__ Oq, __bf16* __restrict__ Ok, __bf16* __restrict__ OvT)
{
  int o = (blockIdx.x % 96) * 8 + blockIdx.x / 96;  // bijective, 768 = 96*8
  int nb = o & 7, mb = (o >> 3) & 31, z = o >> 8;

  const float* X = (z == 0) ? Xq : (z == 1) ? Xk : Xv;
  const __bf16* W = (z == 0) ? Wq : (z == 1) ? Wk : Wv;
  const float* bias = (z == 0) ? bq : (z == 1) ? bk : bv;
  float scale = (z == 0) ? 0.180336880111183f : 1.0f;  // 0.125 * log2(e)

  __shared__ __align__(16) char smem[40960];  // As[2] 16K + Bs[3] 24K; Tt reuses
  bf16x8 (*As)[512] = (bf16x8(*)[512])smem;
  bf16x8 (*Bs)[512] = (bf16x8(*)[512])(smem + 16384);

  int t = threadIdx.x, lane = t & 63, w = t >> 6;
  int l15 = lane & 15, l4 = lane >> 4;
  int wr = w >> 1, wc = w & 1;
  int m0 = mb * 128, n0 = nb * 128;

  int arow = t >> 1, ac2 = (t & 1) * 2;
  const float* Xs = X + (size_t)(m0 + arow) * 1024 + (t & 1) * 16;
  int srow = t >> 2, sc = t & 3;
  const __bf16* Wsp = W + (size_t)(n0 + srow) * 1024 + sc * 8;
  int ldsoff = __builtin_amdgcn_readfirstlane(w * 1024);

  float4 a0, a1, a2, a3;

#define ALOAD(kt)                                                              \
  {                                                                            \
    const float4* ap = (const float4*)(Xs + (size_t)(kt) * 32);                \
    a0 = ap[0]; a1 = ap[1]; a2 = ap[2]; a3 = ap[3];                            \
  }
#define AWRITE(buf)                                                            \
  {                                                                            \
    bf16x8 lo, hi;                                                             \
    lo[0] = (__bf16)a0.x; lo[1] = (__bf16)a0.y; lo[2] = (__bf16)a0.z;          \
    lo[3] = (__bf16)a0.w; lo[4] = (__bf16)a1.x; lo[5] = (__bf16)a1.y;          \
    lo[6] = (__bf16)a1.z; lo[7] = (__bf16)a1.w;                                \
    hi[0] = (__bf16)a2.x; hi[1] = (__bf16)a2.y; hi[2] = (__bf16)a2.z;          \
    hi[3] = (__bf16)a2.w; hi[4] = (__bf16)a3.x; hi[5] = (__bf16)a3.y;          \
    hi[6] = (__bf16)a3.z; hi[7] = (__bf16)a3.w;                                \
    As[buf][arow * 4 + ac2] = lo;                                              \
    As[buf][arow * 4 + ac2 + 1] = hi;                                          \
  }
#define BSTG(buf, kt)                                                          \
  {                                                                            \
    _Pragma("unroll")                                                          \
    for (int i = 0; i < 2; ++i) {                                              \
      int lo_ = __builtin_amdgcn_readfirstlane(i * 4096 + ldsoff);             \
      g2l16(Wsp + (size_t)i * 64 * 1024 + (kt) * 32, (char*)Bs[buf] + lo_);    \
    }                                                                          \
  }

  f32x4 acc[4][4] = {};

  BSTG(0, 0)
  ALOAD(0)
  BSTG(1, 1)
  asm volatile("s_waitcnt vmcnt(2)" ::: "memory");
  AWRITE(0)
  ALOAD(1)
  asm volatile("s_waitcnt lgkmcnt(0)" ::: "memory");
  __builtin_amdgcn_s_barrier();
  __builtin_amdgcn_sched_barrier(0);

  int bring = 0;
  for (int kt = 0; kt < 32; ++kt) {
    int bcur = bring;
    int bp2 = (bring >= 1) ? bring - 1 : 2;
    int acur = kt & 1, anxt = acur ^ 1;
    if (kt + 2 < 32) BSTG(bp2, kt + 2)
    __builtin_amdgcn_sched_barrier(0);

    bf16x8 af[4], bfr[4];
#pragma unroll
    for (int i = 0; i < 4; ++i) af[i] = As[acur][(wr * 64 + i * 16 + l15) * 4 + l4];
#pragma unroll
    for (int j = 0; j < 4; ++j) bfr[j] = Bs[bcur][(wc * 64 + j * 16 + l15) * 4 + l4];
#pragma unroll
    for (int i = 0; i < 4; ++i)
#pragma unroll
      for (int j = 0; j < 4; ++j)
        acc[i][j] = __builtin_amdgcn_mfma_f32_16x16x32_bf16(af[i], bfr[j], acc[i][j], 0, 0, 0);
    __builtin_amdgcn_sched_barrier(0);

    if (kt + 1 < 32) {
      if (kt + 2 < 32) {
        asm volatile("s_waitcnt vmcnt(2)" ::: "memory");
      } else {
        asm volatile("s_waitcnt vmcnt(0)" ::: "memory");
      }
      AWRITE(anxt)
      if (kt + 2 < 32) ALOAD(kt + 2)
      asm volatile("s_waitcnt lgkmcnt(0)" ::: "memory");
      __builtin_amdgcn_s_barrier();
      __builtin_amdgcn_sched_barrier(0);
    }
    bring = (bring == 2) ? 0 : bring + 1;
  }
#undef ALOAD
#undef AWRITE
#undef BSTG

  if (z == 2) {
    __syncthreads();
    __bf16* Tt = (__bf16*)smem;
    const int LDT = 136;
    int b = m0 >> 11, ss0 = m0 & 2047;
#pragma unroll
    for (int p = 0; p < 2; ++p) {
      if (wc == p) {
#pragma unroll
        for (int j = 0; j < 4; ++j) {
          float bv_ = bias[n0 + p * 64 + j * 16 + l15];
#pragma unroll
          for (int i = 0; i < 4; ++i) {
            bf16x4 pv;
#pragma unroll
            for (int r = 0; r < 4; ++r) pv[r] = (__bf16)(acc[i][j][r] + bv_);
            *(bf16x4*)&Tt[(j * 16 + l15) * LDT + wr * 64 + i * 16 + l4 * 4] = pv;
          }
        }
      }
      __syncthreads();
      int h = (n0 >> 6) + p;
      __bf16* dst = OvT + ((size_t)(b * H_ + h) * 64) * S_ + ss0;
#pragma unroll
      for (int it = 0; it < 4; ++it) {
        int nl = it * 16 + (t >> 4);
        int mc = (t & 15) * 8;
        bf16x8 vv = *(bf16x8*)&Tt[nl * LDT + mc];
        *(bf16x8*)(dst + (size_t)nl * S_ + mc) = vv;
      }
      __syncthreads();
    }
  } else {
    __bf16* O = (z == 0) ? Oq : Ok;
#pragma unroll
    for (int j = 0; j < 4; ++j) {
      int col = n0 + wc * 64 + j * 16 + l15;
      float bv_ = bias[col];
      int h = col >> 6, hd = col & 63;
#pragma unroll
      for (int i = 0; i < 4; ++i) {
#pragma unroll
        for (int r = 0; r < 4; ++r) {
          int row = m0 + wr * 64 + i * 16 + l4 * 4 + r;
          int b = row >> 11, ss = row & 2047;
          float val = (acc[i][j][r] + bv_) * scale;
          O[(((size_t)b * H_ + h) * S_ + ss) * 64 + hd] = (__bf16)val;
        }
      }
    }
  }
}

// ---------------- K2: attention, two-sweep, no-max softmax (R7 verbatim) ----
__global__ __launch_bounds__(512, 4) void k_attn(
    const __bf16* __restrict__ Qh, const __bf16* __restrict__ Kh,
    const __bf16* __restrict__ VhT, float* __restrict__ atten,
    __bf16* __restrict__ ctxb)
{
  __shared__ bf16x8 KVl[3][1024];  // 3 x 16KB stages (A: 128 keys; B: 64K + 64V)
  __shared__ bf16x8 Pl[8 * 176];   // per-wave p: [16 rows][11 chunks]

  int bid = blockIdx.x;
  int sb = (bid & 7) * 64 + (bid >> 3);  // XCD swizzle (512 = 8*64, bijective)
  int bh = sb >> 4, qt = sb & 15;
  int t = threadIdx.x, lane = t & 63, w = t >> 6;
  int l15 = lane & 15, l4 = lane >> 4;
  int q0 = qt * 128 + w * 16;

  const __bf16* Qp = Qh + ((size_t)bh * S_ + q0) * 64;
  bf16x8 qf0 = *(const bf16x8*)(Qp + (size_t)l15 * 64 + l4 * 8);
  bf16x8 qf1 = *(const bf16x8*)(Qp + (size_t)l15 * 64 + 32 + l4 * 8);

  int srow = t >> 3, sc8 = t & 7;
  int scs = sc8 ^ (srow & 7);  // pre-swizzled global source (LDS dest linear)
  int wbase = __builtin_amdgcn_readfirstlane(w * 1024);

  const __bf16* KpS = Kh + (size_t)bh * S_ * 64 + (size_t)srow * 64 + scs * 8;
  const __bf16* VpS = VhT + (size_t)bh * 64 * S_ + (size_t)srow * S_ + scs * 8;

  // ---- pass A: softmax denominator; 16 iters x 128 keys, 3-deep ----
  float l_part[4] = {0.f, 0.f, 0.f, 0.f};

#define ASTAGE(buf, kt)                                                        \
  {                                                                            \
    g2l16(KpS + (size_t)(kt) * 8192, (char*)KVl[buf] + wbase);                 \
    g2l16(KpS + (size_t)(kt) * 8192 + 4096, (char*)KVl[buf] + 8192 + wbase);   \
  }

  ASTAGE(0, 0)
  ASTAGE(1, 1)
  asm volatile("s_waitcnt vmcnt(2)" ::: "memory");
  __builtin_amdgcn_s_barrier();
  __builtin_amdgcn_sched_barrier(0);

  {
    int ring = 0;
    for (int kt = 0; kt < 16; ++kt) {
      int cur = ring;
      int rp2 = (ring == 0) ? 2 : ring - 1;
      if (kt + 2 < 16) ASTAGE(rp2, kt + 2)
      __builtin_amdgcn_sched_barrier(0);

#pragma unroll
      for (int t8 = 0; t8 < 8; ++t8) {
        int kr = t8 * 16 + l15;
        bf16x8 kf0 = KVl[cur][kr * 8 + ((l4) ^ (kr & 7))];
        bf16x8 kf1 = KVl[cur][kr * 8 + ((4 + l4) ^ (kr & 7))];
        f32x4 a_ = {0.f, 0.f, 0.f, 0.f};
        a_ = __builtin_amdgcn_mfma_f32_16x16x32_bf16(qf0, kf0, a_, 0, 0, 0);
        a_ = __builtin_amdgcn_mfma_f32_16x16x32_bf16(qf1, kf1, a_, 0, 0, 0);
#pragma unroll
        for (int r = 0; r < 4; ++r) l_part[r] += exp2_hw(a_[r]);
      }

      if (kt < 14) {
        asm volatile("s_waitcnt vmcnt(2)" ::: "memory");
        __builtin_amdgcn_s_barrier();
        __builtin_amdgcn_sched_barrier(0);
      } else if (kt == 14) {
        asm volatile("s_waitcnt vmcnt(0)" ::: "memory");
        __builtin_amdgcn_s_barrier();
        __builtin_amdgcn_sched_barrier(0);
      }
      ring = (ring == 2) ? 0 : ring + 1;
    }
  }
#undef ASTAGE

  float inv_l[4];
#pragma unroll
  for (int r = 0; r < 4; ++r) {
    float l = l_part[r];
    l += __shfl_xor(l, 1);
    l += __shfl_xor(l, 2);
    l += __shfl_xor(l, 4);
    l += __shfl_xor(l, 8);
    inv_l[r] = 1.0f / l;
  }

  __builtin_amdgcn_s_barrier();
  __builtin_amdgcn_sched_barrier(0);

  // ---- pass B: write atten + accumulate ctx; 32 iters x 64 keys ----
  f32x4 ctx[4] = {};
  float* aRow = atten + ((size_t)bh * S_ + q0) * S_;
  __bf16* PlW = (__bf16*)(Pl + w * 176);

#define BSTAGE(buf, kt)                                                        \
  {                                                                            \
    g2l16(KpS + (size_t)(kt) * 4096, (char*)KVl[buf] + wbase);                 \
    g2l16(VpS + (size_t)(kt) * 64, (char*)KVl[buf] + 8192 + wbase);            \
  }

  BSTAGE(0, 0)
  BSTAGE(1, 1)
  asm volatile("s_waitcnt vmcnt(2)" ::: "memory");
  __builtin_amdgcn_s_barrier();
  __builtin_amdgcn_sched_barrier(0);

  {
    int ring = 0;
    for (int kt = 0; kt < 32; ++kt) {
      int cur = ring;
      int rp2 = (ring == 0) ? 2 : ring - 1;
      if (kt + 2 < 32) BSTAGE(rp2, kt + 2)
      __builtin_amdgcn_sched_barrier(0);

      f32x4 sc[4];
#pragma unroll
      for (int t8 = 0; t8 < 4; ++t8) {
        int kr = t8 * 16 + l15;
        bf16x8 kf0 = KVl[cur][kr * 8 + ((l4) ^ (kr & 7))];
        bf16x8 kf1 = KVl[cur][kr * 8 + ((4 + l4) ^ (kr & 7))];
        f32x4 a_ = {0.f, 0.f, 0.f, 0.f};
        a_ = __builtin_amdgcn_mfma_f32_16x16x32_bf16(qf0, kf0, a_, 0, 0, 0);
        a_ = __builtin_amdgcn_mfma_f32_16x16x32_bf16(qf1, kf1, a_, 0, 0, 0);
        sc[t8] = a_;
      }

#pragma unroll
      for (int t8 = 0; t8 < 4; ++t8) {
#pragma unroll
        for (int r = 0; r < 4; ++r) {
          float p = exp2_hw(sc[t8][r]) * inv_l[r];
          aRow[(size_t)(l4 * 4 + r) * S_ + kt * 64 + t8 * 16 + l15] = p;
          PlW[(l4 * 4 + r) * 88 + t8 * 16 + l15] = (__bf16)p;
        }
      }

#pragma unroll
      for (int kc = 0; kc < 2; ++kc) {
        bf16x8 pa = Pl[w * 176 + l15 * 11 + kc * 4 + l4];
#pragma unroll
        for (int dt = 0; dt < 4; ++dt) {
          int vr = dt * 16 + l15;
          bf16x8 vf = KVl[cur][512 + vr * 8 + ((kc * 4 + l4) ^ (vr & 7))];
          ctx[dt] = __builtin_amdgcn_mfma_f32_16x16x32_bf16(pa, vf, ctx[dt], 0, 0, 0);
        }
      }

      if (kt < 31) {
        asm volatile("s_waitcnt vmcnt(18)" ::: "memory");
        __builtin_amdgcn_s_barrier();
        __builtin_amdgcn_sched_barrier(0);
      }
      ring = (ring == 2) ? 0 : ring + 1;
    }
  }
#undef BSTAGE

  int b = bh >> 4, h = bh & 15;
#pragma unroll
  for (int dt = 0; dt < 4; ++dt) {
#pragma unroll
    for (int r = 0; r < 4; ++r) {
      size_t row = (size_t)b * S_ + q0 + l4 * 4 + r;
      ctxb[row * D_ + h * 64 + dt * 16 + l15] = (__bf16)ctx[dt][r];
    }
  }
}

// ---------------- K3: output projection -> fp32 d_out (XCD-clustered) ------
__global__ __launch_bounds__(256, 3) void k_out(
    const __bf16* __restrict__ X, const __bf16* __restrict__ W,
    const float* __restrict__ bias, float* __restrict__ O)
{
  __shared__ bf16x8 As[3][512];
  __shared__ bf16x8 Bs[3][512];

  int o = (blockIdx.x % 32) * 8 + blockIdx.x / 32;  // bijective, 256 = 32*8
  int nb = o & 7, mb = o >> 3;

  int t = threadIdx.x, lane = t & 63, w = t >> 6;
  int l15 = lane & 15, l4 = lane >> 4;
  int wr = w >> 1, wc = w & 1;
  int m0 = mb * 128, n0 = nb * 128;

  int srow = t >> 2, sc = t & 3;
  int ldsoff = __builtin_amdgcn_readfirstlane(w * 1024);
  const __bf16* Xs = X + (size_t)(m0 + srow) * 1024 + sc * 8;
  const __bf16* Wsp = W + (size_t)(n0 + srow) * 1024 + sc * 8;

#define PSTAGE(buf, kt)                                                        \
  {                                                                            \
    _Pragma("unroll")                                                          \
    for (int i = 0; i < 2; ++i) {                                              \
      int lo = __builtin_amdgcn_readfirstlane(i * 4096 + ldsoff);              \
      g2l16(Xs + (size_t)i * 64 * 1024 + (kt) * 32, (char*)As[buf] + lo);      \
      g2l16(Wsp + (size_t)i * 64 * 1024 + (kt) * 32, (char*)Bs[buf] + lo);     \
    }                                                                          \
  }

  f32x4 acc[4][4] = {};

  PSTAGE(0, 0)
  PSTAGE(1, 1)
  asm volatile("s_waitcnt vmcnt(4)" ::: "memory");
  __builtin_amdgcn_s_barrier();
  __builtin_amdgcn_sched_barrier(0);

  int ring = 0;
  for (int kt = 0; kt < 32; ++kt) {
    int cur = ring;
    int rp2 = (ring == 0) ? 2 : ring - 1;
    if (kt + 2 < 32) PSTAGE(rp2, kt + 2)
    __builtin_amdgcn_sched_barrier(0);

    bf16x8 af[4], bfr[4];
#pragma unroll
    for (int i = 0; i < 4; ++i) af[i] = As[cur][(wr * 64 + i * 16 + l15) * 4 + l4];
#pragma unroll
    for (int j = 0; j < 4; ++j) bfr[j] = Bs[cur][(wc * 64 + j * 16 + l15) * 4 + l4];
#pragma unroll
    for (int i = 0; i < 4; ++i)
#pragma unroll
      for (int j = 0; j < 4; ++j)
        acc[i][j] = __builtin_amdgcn_mfma_f32_16x16x32_bf16(af[i], bfr[j], acc[i][j], 0, 0, 0);

    if (kt < 30) {
      asm volatile("s_waitcnt vmcnt(4)" ::: "memory");
      __builtin_amdgcn_s_barrier();
      __builtin_amdgcn_sched_barrier(0);
    } else if (kt == 30) {
      asm volatile("s_waitcnt vmcnt(0)" ::: "memory");
      __builtin_amdgcn_s_barrier();
      __builtin_amdgcn_sched_barrier(0);
    }
    ring = (ring == 2) ? 0 : ring + 1;
  }
#undef PSTAGE

#pragma unroll
  for (int j = 0; j < 4; ++j) {
    int col = n0 + wc * 64 + j * 16 + l15;
    float bv_ = bias[col];
#pragma unroll
    for (int i = 0; i < 4; ++i) {
#pragma unroll
      for (int r = 0; r < 4; ++r) {
        int row = m0 + wr * 64 + i * 16 + l4 * 4 + r;
        O[(size_t)row * 1024 + col] = acc[i][j][r] + bv_;
      }
    }
  }
}

// ---------------- launch ----------------
extern "C" void kernel_launch(void* const* d_in, const int* in_sizes, int n_in,
                              void* d_out, int out_size, void* d_ws, size_t ws_size,
                              hipStream_t stream)
{
  const float* q  = (const float*)d_in[0];
  const float* k  = (const float*)d_in[1];
  const float* v  = (const float*)d_in[2];
  const float* Wq = (const float*)d_in[3];
  const float* bq = (const float*)d_in[4];
  const float* Wk = (const float*)d_in[5];
  const float* bk = (const float*)d_in[6];
  const float* Wv = (const float*)d_in[7];
  const float* bv = (const float*)d_in[8];
  const float* Wo = (const float*)d_in[9];
  const float* bo = (const float*)d_in[10];

  const size_t NBSD = (size_t)B_ * S_ * D_;   // 4194304
  const size_t NDD  = (size_t)D_ * D_;        // 1048576

  float* out = (float*)d_out;
  float* atten = out + NBSD;

  if (ws_size < (4 * NDD + 4 * NBSD) * 2) return;  // ~41.9 MB needed

  __bf16* ws = (__bf16*)d_ws;
  __bf16* Wqb = ws;
  __bf16* Wkb = Wqb + NDD;
  __bf16* Wvb = Wkb + NDD;
  __bf16* Wob = Wvb + NDD;
  __bf16* Qh  = Wob + NDD;
  __bf16* Kh  = Qh + NBSD;
  __bf16* VhT = Kh + NBSD;
  __bf16* ctxb = VhT + NBSD;

  CvtArgs ca;
  ca.s[0] = Wq; ca.d[0] = Wqb;
  ca.s[1] = Wk; ca.d[1] = Wkb;
  ca.s[2] = Wv; ca.d[2] = Wvb;
  ca.s[3] = Wo; ca.d[3] = Wob;

  k_cvt<<<dim3(512, 4), 256, 0, stream>>>(ca);
  k_proj<<<dim3(768), 256, 0, stream>>>(q, k, v, Wqb, Wkb, Wvb,
                                        bq, bk, bv, Qh, Kh, VhT);
  k_attn<<<dim3(512), 512, 0, stream>>>(Qh, Kh, VhT, atten, ctxb);
  k_out<<<dim3(256), 256, 0, stream>>>(ctxb, Wob, bo, out);
}